// Round 21
// baseline (166.908 us; speedup 1.0000x reference)
//
#include <hip/hip_runtime.h>
#include <math.h>

#define Bn 16
#define Cn 64
#define Hn 192
#define Wn 192
#define NPIX (Bn * Cn * Hn * Wn)   // 37748736
#define NBLKS 512
#define WCOLS 98
#define SLOTB (WCOLS * 128)        // 12544 B per window row-slot

typedef short bf16x8 __attribute__((ext_vector_type(8)));
typedef float f32x4 __attribute__((ext_vector_type(4)));
typedef __attribute__((address_space(1))) const unsigned int as1_u32;
typedef __attribute__((address_space(3))) unsigned int as3_u32;

// g_Ms[9 slices][64 rows][64 c] bf16; within a row, c-octet g stored at slot (g ^ (p&7)).
__device__ __align__(16) unsigned short g_Ms[9 * 64 * 64];
__device__ __align__(16) float g_b2[64];

static __device__ __forceinline__ unsigned short f2bf(float f) {
    union { float f; unsigned u; } x; x.f = f;
    unsigned r = x.u + 0x7fffu + ((x.u >> 16) & 1u);   // RNE
    return (unsigned short)(r >> 16);
}

__global__ void acdc_precompute(const float* __restrict__ cw, const float* __restrict__ A,
                                const float* __restrict__ D, const float* __restrict__ bias,
                                const int* __restrict__ perm) {
    __shared__ float mre[64];
    int p = blockIdx.x;
    int t = threadIdx.x;
    if (t < 64) {
        float re = 0.f;
        for (int k = 0; k < 64; ++k) {
            int a = (k * t) & 63;
            re += D[k] * cosf((float)a * 0.0981747704246810387f);  // pi/32
        }
        mre[t] = re;
    }
    __syncthreads();
    int pp = perm[p];
    for (int k0 = t; k0 < 576; k0 += 256) {
        int sp = k0 >> 6, c = k0 & 63;
        int g = c >> 3, cil = c & 7;
        float val = 0.f;
        for (int o = 0; o < 8; ++o) {
            int oc = g * 8 + o;
            float gco = mre[(pp - oc + 64) & 63] * A[oc] * (0.125f / 64.0f);
            val += gco * cw[(oc * 8 + cil) * 9 + sp];
        }
        g_Ms[((sp * 64 + p) << 6) + (((g ^ (p & 7)) << 3) | cil)] = f2bf(val);
    }
    if (p == 0 && t < 64)
        g_b2[t] = bias[perm[t]] * 0.125f;
}

// 512 blocks x 1024 thr. Block = image x 12-row band x half width. 4-row steps,
// 6-slot window, wave = 2m x 3n (5 LDS reads / 6 MFMAs). M in LDS once.
// __launch_bounds__(1024, 4): 4 waves/EU = 1 block/CU -> VGPR cap 128. Without it
// the compiler clamps 1024-thread kernels to 64 VGPR -> R20's acc+staging spilled
// (WRITE 309MB). One-variable fix of R20.
__global__ __launch_bounds__(1024, 4)
void acdc_main(const float* __restrict__ x, float* __restrict__ out) {
    __shared__ __align__(16) unsigned short Mlds[9 * 64 * 64];   // 73728 B
    __shared__ __align__(16) unsigned char xsb[6 * SLOTB];       // 75264 B

    int tid = threadIdx.x;
    int lane = tid & 63, wv = tid >> 6;
    // bijective XCD swizzle (512 % 8 == 0): XCD k gets 64 consecutive logical blocks
    int Lb = (blockIdx.x & 7) * (NBLKS / 8) + (blockIdx.x >> 3);
    int bb = Lb >> 5;                 // image
    int band = (Lb >> 1) & 15;        // 12-row band
    int half = Lb & 1;                // width half
    int h0 = band * 12;
    int cbase = half * 96;

    // ---- stage M once: 72 x 1KB chunks via global_load_lds ----
    #pragma unroll
    for (int k = 0; k < 5; ++k) {
        int chunk = wv + k * 16;
        if (chunk < 72) {
            const unsigned char* src = (const unsigned char*)g_Ms + chunk * 1024 + lane * 16;
            __builtin_amdgcn_global_load_lds((as1_u32*)(const void*)src,
                (as3_u32*)(void*)((unsigned char*)Mlds + chunk * 1024), 16, 0, 0);
        }
    }

    int pxw = lane & 15, q = lane >> 4, rlane = lane & 15;
    int r = wv & 3;                   // row within 4-row step
    int mg = (wv >> 2) & 1;           // m-pair: m-tiles {2mg, 2mg+1}
    int ngg = wv >> 3;                // n-group: 3 n-tiles at cols ngg*48..+47

    const float* xb = x + (size_t)bb * Cn * Hn * Wn;

    // ---- prologue: stage rows h0-1 .. h0+4 -> slots 0..5 (fused load+write) ----
    for (int k = 0; k < 5; ++k) {
        int idx = tid + (k << 10);
        if (idx >= 4992) break;
        int f = idx % 26;
        int rr = (idx / 26) % 6;
        int cp = idx / 156;
        int gi = h0 - 1 + rr;
        int gc0 = cbase - 4 + 4 * f;
        float av[4] = {0.f, 0.f, 0.f, 0.f}, bv[4] = {0.f, 0.f, 0.f, 0.f};
        bool giok = (unsigned)gi < (unsigned)Hn;
        const float* r0 = xb + ((size_t)(2 * cp) * Hn + (giok ? gi : 0)) * Wn;
        const float* r1 = r0 + Hn * Wn;
        if (giok) {
            if (gc0 >= 0 && gc0 <= Wn - 4) {
                float4 a = *(const float4*)(r0 + gc0);
                float4 b = *(const float4*)(r1 + gc0);
                av[0]=a.x; av[1]=a.y; av[2]=a.z; av[3]=a.w;
                bv[0]=b.x; bv[1]=b.y; bv[2]=b.z; bv[3]=b.w;
            } else {
                #pragma unroll
                for (int j = 0; j < 4; ++j) {
                    int gc = gc0 + j;
                    if ((unsigned)gc < (unsigned)Wn) { av[j] = r0[gc]; bv[j] = r1[gc]; }
                }
            }
        }
        int slot = rr;                       // (gi+1)%6 == rr since h0%6==0
        int chunk = cp >> 2, sub = (cp & 3) * 4;
        #pragma unroll
        for (int j = 0; j < 4; ++j) {
            int c2 = 4 * f + j - 3;
            if ((unsigned)c2 >= (unsigned)WCOLS) continue;
            unsigned u;
            asm("v_cvt_pk_bf16_f32 %0, %1, %2" : "=v"(u) : "v"(av[j]), "v"(bv[j]));
            int key = (c2 + (c2 >> 3) + 3 * slot) & 7;
            *(unsigned*)(xsb + slot * SLOTB + c2 * 128 + ((chunk ^ key) << 4) + sub) = u;
        }
    }
    __syncthreads();   // publishes M + initial 6-row window

    float4 va[4], vb[4];
    for (int t = 0; t < 3; ++t) {
        int hb = h0 + 4 * t;
        int S = (t == 0) ? 0 : (t == 1) ? 4 : 2;      // hb % 6

        // ---- xload: rows hb+5..hb+8 to regs (retires under compute) ----
        if (t < 2) {
            #pragma unroll
            for (int k = 0; k < 4; ++k) {
                int idx = tid + (k << 10);
                va[k] = (float4){0.f,0.f,0.f,0.f};
                vb[k] = (float4){0.f,0.f,0.f,0.f};
                if (idx >= 3328) continue;
                int f = idx % 26;
                int rr = (idx / 26) & 3;
                int cp = idx / 104;
                int gi = hb + 5 + rr;
                int gc0 = cbase - 4 + 4 * f;
                bool giok = (unsigned)gi < (unsigned)Hn;
                const float* r0 = xb + ((size_t)(2 * cp) * Hn + (giok ? gi : 0)) * Wn;
                const float* r1 = r0 + Hn * Wn;
                if (giok) {
                    if (gc0 >= 0 && gc0 <= Wn - 4) {
                        va[k] = *(const float4*)(r0 + gc0);
                        vb[k] = *(const float4*)(r1 + gc0);
                    } else {
                        float t0[4] = {0,0,0,0}, t1[4] = {0,0,0,0};
                        #pragma unroll
                        for (int j = 0; j < 4; ++j) {
                            int gc = gc0 + j;
                            if ((unsigned)gc < (unsigned)Wn) { t0[j] = r0[gc]; t1[j] = r1[gc]; }
                        }
                        va[k] = (float4){t0[0], t0[1], t0[2], t0[3]};
                        vb[k] = (float4){t1[0], t1[1], t1[2], t1[3]};
                    }
                }
            }
        }

        // ---- compute: wave row hb+r, 2m x 3n, barrier-free ----
        f32x4 acc[2][3];
        #pragma unroll
        for (int mi = 0; mi < 2; ++mi)
            #pragma unroll
            for (int i = 0; i < 3; ++i)
                acc[mi][i] = (f32x4){0.f, 0.f, 0.f, 0.f};

        #pragma unroll
        for (int sp = 0; sp < 9; ++sp) {
            const int dy = sp / 3, dx = sp % 3;
            int v = S + r + dy; if (v >= 6) v -= 6;    // slot of input row hb+r+dy-1
            int sb = v * SLOTB;
            int k3 = 3 * v;
            int c2base = ngg * 48 + pxw + dx;
            #pragma unroll
            for (int kh = 0; kh < 2; ++kh) {
                int ksl = kh * 4 + q;
                const unsigned char* mrow = (const unsigned char*)Mlds + sp * 8192 +
                                            rlane * 128 + ((ksl ^ (rlane & 7)) << 4);
                bf16x8 am0 = *(const bf16x8*)(mrow + (2 * mg) * 2048);
                bf16x8 am1 = *(const bf16x8*)(mrow + (2 * mg + 1) * 2048);
                bf16x8 bfr[3];
                #pragma unroll
                for (int i = 0; i < 3; ++i) {
                    int c2 = c2base + i * 16;
                    int key = (c2 + (c2 >> 3) + k3) & 7;
                    bfr[i] = *(const bf16x8*)(xsb + sb + c2 * 128 + ((ksl ^ key) << 4));
                }
                __builtin_amdgcn_s_setprio(1);
                #pragma unroll
                for (int i = 0; i < 3; ++i)
                    acc[0][i] = __builtin_amdgcn_mfma_f32_16x16x32_bf16(am0, bfr[i], acc[0][i], 0, 0, 0);
                #pragma unroll
                for (int i = 0; i < 3; ++i)
                    acc[1][i] = __builtin_amdgcn_mfma_f32_16x16x32_bf16(am1, bfr[i], acc[1][i], 0, 0, 0);
                __builtin_amdgcn_s_setprio(0);
            }
        }

        // ---- epilogue: +bias, real-only stores (row hb+r) ----
        {
            int h = hb + r;
            #pragma unroll
            for (int mi = 0; mi < 2; ++mi) {
                int rbase = (2 * mg + mi) * 16 + q * 4;
                float4 bq = *(const float4*)(g_b2 + rbase);
                float bvs[4] = {bq.x, bq.y, bq.z, bq.w};
                #pragma unroll
                for (int i = 0; i < 3; ++i) {
                    int px = cbase + ngg * 48 + i * 16 + pxw;
                    #pragma unroll
                    for (int jj = 0; jj < 4; ++jj)
                        out[(((size_t)(bb * Cn + rbase + jj)) * Hn + h) * Wn + px] =
                            acc[mi][i][jj] + bvs[jj];
                }
            }
        }

        __syncthreads();                  // all window reads for this step done

        // ---- xwrite: rows hb+5..hb+8 into retiring slots ----
        if (t < 2) {
            #pragma unroll
            for (int k = 0; k < 4; ++k) {
                int idx = tid + (k << 10);
                if (idx >= 3328) continue;
                int f = idx % 26;
                int rr = (idx / 26) & 3;
                int cp = idx / 104;
                int vslot = S + rr; if (vslot >= 6) vslot -= 6;   // (hb+6+rr)%6
                int chunk = cp >> 2, sub = (cp & 3) * 4;
                float v0[4] = {va[k].x, va[k].y, va[k].z, va[k].w};
                float v1[4] = {vb[k].x, vb[k].y, vb[k].z, vb[k].w};
                #pragma unroll
                for (int j = 0; j < 4; ++j) {
                    int c2 = 4 * f + j - 3;
                    if ((unsigned)c2 >= (unsigned)WCOLS) continue;
                    unsigned u;
                    asm("v_cvt_pk_bf16_f32 %0, %1, %2" : "=v"(u) : "v"(v0[j]), "v"(v1[j]));
                    int key = (c2 + (c2 >> 3) + 3 * vslot) & 7;
                    *(unsigned*)(xsb + vslot * SLOTB + c2 * 128 + ((chunk ^ key) << 4) + sub) = u;
                }
            }
        }
        __syncthreads();                  // publish new rows
    }
}

extern "C" void kernel_launch(void* const* d_in, const int* in_sizes, int n_in,
                              void* d_out, int out_size, void* d_ws, size_t ws_size,
                              hipStream_t stream) {
    const float* x    = (const float*)d_in[0];
    const float* cw   = (const float*)d_in[1];
    const float* A    = (const float*)d_in[2];
    const float* D    = (const float*)d_in[3];
    const float* bias = (const float*)d_in[4];
    const int*   perm = (const int*)d_in[5];

    acdc_precompute<<<dim3(64), dim3(256), 0, stream>>>(cw, A, D, bias, perm);
    acdc_main<<<dim3(NBLKS), dim3(1024), 0, stream>>>(x, (float*)d_out);
}

// Round 22
// 163.695 us; speedup vs baseline: 1.0196x; 1.0196x over previous
//
#include <hip/hip_runtime.h>
#include <math.h>

#define Bn 16
#define Cn 64
#define Hn 192
#define Wn 192
#define NPIX (Bn * Cn * Hn * Wn)   // 37748736
#define NBLKS 512
#define WCOLS 98
#define SLOTB (WCOLS * 128)        // 12544 B per window row-slot

typedef short bf16x8 __attribute__((ext_vector_type(8)));
typedef float f32x16 __attribute__((ext_vector_type(16)));
typedef __attribute__((address_space(1))) const unsigned int as1_u32;
typedef __attribute__((address_space(3))) unsigned int as3_u32;

// g_Ms[9 slices][64 rows][64 c] bf16; within a row, c-octet g stored at slot (g ^ (p&7)).
__device__ __align__(16) unsigned short g_Ms[9 * 64 * 64];
__device__ __align__(16) float g_b2[64];

static __device__ __forceinline__ unsigned short f2bf(float f) {
    union { float f; unsigned u; } x; x.f = f;
    unsigned r = x.u + 0x7fffu + ((x.u >> 16) & 1u);   // RNE
    return (unsigned short)(r >> 16);
}

__global__ void acdc_precompute(const float* __restrict__ cw, const float* __restrict__ A,
                                const float* __restrict__ D, const float* __restrict__ bias,
                                const int* __restrict__ perm) {
    __shared__ float mre[64];
    int p = blockIdx.x;
    int t = threadIdx.x;
    if (t < 64) {
        float re = 0.f;
        for (int k = 0; k < 64; ++k) {
            int a = (k * t) & 63;
            re += D[k] * cosf((float)a * 0.0981747704246810387f);  // pi/32
        }
        mre[t] = re;
    }
    __syncthreads();
    int pp = perm[p];
    for (int k0 = t; k0 < 576; k0 += 256) {
        int sp = k0 >> 6, c = k0 & 63;
        int g = c >> 3, cil = c & 7;
        float val = 0.f;
        for (int o = 0; o < 8; ++o) {
            int oc = g * 8 + o;
            float gco = mre[(pp - oc + 64) & 63] * A[oc] * (0.125f / 64.0f);
            val += gco * cw[(oc * 8 + cil) * 9 + sp];
        }
        g_Ms[((sp * 64 + p) << 6) + (((g ^ (p & 7)) << 3) | cil)] = f2bf(val);
    }
    if (p == 0 && t < 64)
        g_b2[t] = bias[perm[t]] * 0.125f;
}

// 512 blocks x 1024 thr. Block = image x 12-row band x half width. 4-row steps,
// 6-slot window, M in LDS once. COMPUTE: mfma_f32_32x32x16_bf16, 12 active waves
// (4 rows x 3 32px-tiles), each wave does both 32ch m-tiles: per k-step
// 1 B-read + 2 A-reads for 2 MFMA-32 (= 0.75 b128 / 16K-FLOP, -44% vs R19).
// acc = 2 x f32x16 AGPR; arch regs ~56 < the empirical 64-cap of 1024-thr kernels.
__global__ __launch_bounds__(1024)
void acdc_main(const float* __restrict__ x, float* __restrict__ out) {
    __shared__ __align__(16) unsigned short Mlds[9 * 64 * 64];   // 73728 B
    __shared__ __align__(16) unsigned char xsb[6 * SLOTB];       // 75264 B

    int tid = threadIdx.x;
    int lane = tid & 63, wv = tid >> 6;
    // bijective XCD swizzle (512 % 8 == 0)
    int Lb = (blockIdx.x & 7) * (NBLKS / 8) + (blockIdx.x >> 3);
    int bb = Lb >> 5;                 // image
    int band = (Lb >> 1) & 15;        // 12-row band
    int half = Lb & 1;                // width half
    int h0 = band * 12;
    int cbase = half * 96;

    // ---- stage M once: 72 x 1KB chunks via global_load_lds ----
    #pragma unroll
    for (int k = 0; k < 5; ++k) {
        int chunk = wv + k * 16;
        if (chunk < 72) {
            const unsigned char* src = (const unsigned char*)g_Ms + chunk * 1024 + lane * 16;
            __builtin_amdgcn_global_load_lds((as1_u32*)(const void*)src,
                (as3_u32*)(void*)((unsigned char*)Mlds + chunk * 1024), 16, 0, 0);
        }
    }

    const float* xb = x + (size_t)bb * Cn * Hn * Wn;

    // ---- prologue: stage rows h0-1 .. h0+4 -> slots 0..5 ----
    for (int k = 0; k < 5; ++k) {
        int idx = tid + (k << 10);
        if (idx >= 4992) break;
        int f = idx % 26;
        int rr = (idx / 26) % 6;
        int cp = idx / 156;
        int gi = h0 - 1 + rr;
        int gc0 = cbase - 4 + 4 * f;
        float av[4] = {0.f, 0.f, 0.f, 0.f}, bv[4] = {0.f, 0.f, 0.f, 0.f};
        bool giok = (unsigned)gi < (unsigned)Hn;
        const float* r0 = xb + ((size_t)(2 * cp) * Hn + (giok ? gi : 0)) * Wn;
        const float* r1 = r0 + Hn * Wn;
        if (giok) {
            if (gc0 >= 0 && gc0 <= Wn - 4) {
                float4 a = *(const float4*)(r0 + gc0);
                float4 b = *(const float4*)(r1 + gc0);
                av[0]=a.x; av[1]=a.y; av[2]=a.z; av[3]=a.w;
                bv[0]=b.x; bv[1]=b.y; bv[2]=b.z; bv[3]=b.w;
            } else {
                #pragma unroll
                for (int j = 0; j < 4; ++j) {
                    int gc = gc0 + j;
                    if ((unsigned)gc < (unsigned)Wn) { av[j] = r0[gc]; bv[j] = r1[gc]; }
                }
            }
        }
        int slot = rr;
        int chunk = cp >> 2, sub = (cp & 3) * 4;
        #pragma unroll
        for (int j = 0; j < 4; ++j) {
            int c2 = 4 * f + j - 3;
            if ((unsigned)c2 >= (unsigned)WCOLS) continue;
            unsigned u;
            asm("v_cvt_pk_bf16_f32 %0, %1, %2" : "=v"(u) : "v"(av[j]), "v"(bv[j]));
            int key = (c2 + (c2 >> 3) + 3 * slot) & 7;
            *(unsigned*)(xsb + slot * SLOTB + c2 * 128 + ((chunk ^ key) << 4) + sub) = u;
        }
    }
    __syncthreads();   // publishes M + initial 6-row window

    int l31 = lane & 31, lh = lane >> 5;

    float4 va[4], vb[4];
    for (int t = 0; t < 3; ++t) {
        int hb = h0 + 4 * t;
        int S = (t == 0) ? 0 : (t == 1) ? 4 : 2;      // hb % 6

        // ---- xload: rows hb+5..hb+8 to regs (retires under compute) ----
        if (t < 2) {
            #pragma unroll
            for (int k = 0; k < 4; ++k) {
                int idx = tid + (k << 10);
                va[k] = (float4){0.f,0.f,0.f,0.f};
                vb[k] = (float4){0.f,0.f,0.f,0.f};
                if (idx >= 3328) continue;
                int f = idx % 26;
                int rr = (idx / 26) & 3;
                int cp = idx / 104;
                int gi = hb + 5 + rr;
                int gc0 = cbase - 4 + 4 * f;
                bool giok = (unsigned)gi < (unsigned)Hn;
                const float* r0 = xb + ((size_t)(2 * cp) * Hn + (giok ? gi : 0)) * Wn;
                const float* r1 = r0 + Hn * Wn;
                if (giok) {
                    if (gc0 >= 0 && gc0 <= Wn - 4) {
                        va[k] = *(const float4*)(r0 + gc0);
                        vb[k] = *(const float4*)(r1 + gc0);
                    } else {
                        float t0[4] = {0,0,0,0}, t1[4] = {0,0,0,0};
                        #pragma unroll
                        for (int j = 0; j < 4; ++j) {
                            int gc = gc0 + j;
                            if ((unsigned)gc < (unsigned)Wn) { t0[j] = r0[gc]; t1[j] = r1[gc]; }
                        }
                        va[k] = (float4){t0[0], t0[1], t0[2], t0[3]};
                        vb[k] = (float4){t1[0], t1[1], t1[2], t1[3]};
                    }
                }
            }
        }

        // ---- compute: 12 active waves; wave = (row rr, 32px-tile nt); both m-tiles ----
        if (wv < 12) {
            int rr = wv & 3;
            int nt = wv >> 2;
            f32x16 acc0, acc1;
            #pragma unroll
            for (int e = 0; e < 16; ++e) { acc0[e] = 0.f; acc1[e] = 0.f; }

            #pragma unroll
            for (int sp = 0; sp < 9; ++sp) {
                const int dy = sp / 3, dx = sp % 3;
                int v = S + rr + dy; if (v >= 6) v -= 6;   // slot of input row hb+rr+dy-1
                int c2 = nt * 32 + l31 + dx;
                int key = (c2 + (c2 >> 3) + 3 * v) & 7;
                const unsigned char* bbase = xsb + v * SLOTB + c2 * 128;
                const unsigned char* abase = (const unsigned char*)Mlds + sp * 8192 + l31 * 128;
                #pragma unroll
                for (int ks = 0; ks < 4; ++ks) {
                    int o = 2 * ks + lh;                   // channel octet of this k-half
                    bf16x8 bfr = *(const bf16x8*)(bbase + ((o ^ key) << 4));
                    const unsigned char* ap = abase + ((o ^ (l31 & 7)) << 4);
                    bf16x8 am0 = *(const bf16x8*)ap;
                    bf16x8 am1 = *(const bf16x8*)(ap + 4096);   // p+32: same slot, +32*128
                    __builtin_amdgcn_s_setprio(1);
                    acc0 = __builtin_amdgcn_mfma_f32_32x32x16_bf16(am0, bfr, acc0, 0, 0, 0);
                    acc1 = __builtin_amdgcn_mfma_f32_32x32x16_bf16(am1, bfr, acc1, 0, 0, 0);
                    __builtin_amdgcn_s_setprio(0);
                }
            }

            // ---- epilogue: +bias; C/D: ch = (r&3)+8*(r>>2)+4*lh (+32m), px = l31 ----
            int h = hb + rr;
            int pxg = cbase + nt * 32 + l31;
            #pragma unroll
            for (int r = 0; r < 16; ++r) {
                int chq = (r & 3) + 8 * (r >> 2) + 4 * lh;
                out[(((size_t)(bb * Cn + chq)) * Hn + h) * Wn + pxg]      = acc0[r] + g_b2[chq];
                out[(((size_t)(bb * Cn + 32 + chq)) * Hn + h) * Wn + pxg] = acc1[r] + g_b2[32 + chq];
            }
        }

        __syncthreads();                  // all window reads for this step done

        // ---- xwrite: rows hb+5..hb+8 into retiring slots ----
        if (t < 2) {
            #pragma unroll
            for (int k = 0; k < 4; ++k) {
                int idx = tid + (k << 10);
                if (idx >= 3328) continue;
                int f = idx % 26;
                int rr = (idx / 26) & 3;
                int cp = idx / 104;
                int vslot = S + rr; if (vslot >= 6) vslot -= 6;   // (hb+6+rr)%6
                int chunk = cp >> 2, sub = (cp & 3) * 4;
                float v0[4] = {va[k].x, va[k].y, va[k].z, va[k].w};
                float v1[4] = {vb[k].x, vb[k].y, vb[k].z, vb[k].w};
                #pragma unroll
                for (int j = 0; j < 4; ++j) {
                    int c2 = 4 * f + j - 3;
                    if ((unsigned)c2 >= (unsigned)WCOLS) continue;
                    unsigned u;
                    asm("v_cvt_pk_bf16_f32 %0, %1, %2" : "=v"(u) : "v"(v0[j]), "v"(v1[j]));
                    int key = (c2 + (c2 >> 3) + 3 * vslot) & 7;
                    *(unsigned*)(xsb + vslot * SLOTB + c2 * 128 + ((chunk ^ key) << 4) + sub) = u;
                }
            }
        }
        __syncthreads();                  // publish new rows
    }
}

extern "C" void kernel_launch(void* const* d_in, const int* in_sizes, int n_in,
                              void* d_out, int out_size, void* d_ws, size_t ws_size,
                              hipStream_t stream) {
    const float* x    = (const float*)d_in[0];
    const float* cw   = (const float*)d_in[1];
    const float* A    = (const float*)d_in[2];
    const float* D    = (const float*)d_in[3];
    const float* bias = (const float*)d_in[4];
    const int*   perm = (const int*)d_in[5];

    acdc_precompute<<<dim3(64), dim3(256), 0, stream>>>(cw, A, D, bias, perm);
    acdc_main<<<dim3(NBLKS), dim3(1024), 0, stream>>>(x, (float*)d_out);
}

// Round 23
// 100.680 us; speedup vs baseline: 1.6578x; 1.6259x over previous
//
#include <hip/hip_runtime.h>
#include <math.h>

#define Bn 16
#define Cn 64
#define Hn 192
#define Wn 192
#define NPIX (Bn * Cn * Hn * Wn)   // 37748736
#define NBLKS 512
#define WCOLS 98
#define SLOTB (WCOLS * 128)        // 12544 B per window row-slot

typedef short bf16x8 __attribute__((ext_vector_type(8)));
typedef float f32x16 __attribute__((ext_vector_type(16)));
typedef __attribute__((address_space(1))) const unsigned int as1_u32;
typedef __attribute__((address_space(3))) unsigned int as3_u32;

// g_Ms[9 slices][64 rows][64 c] bf16; within a row, c-octet g stored at slot (g ^ (p&7)).
__device__ __align__(16) unsigned short g_Ms[9 * 64 * 64];
__device__ __align__(16) float g_b2[64];

static __device__ __forceinline__ unsigned short f2bf(float f) {
    union { float f; unsigned u; } x; x.f = f;
    unsigned r = x.u + 0x7fffu + ((x.u >> 16) & 1u);   // RNE
    return (unsigned short)(r >> 16);
}

__global__ void acdc_precompute(const float* __restrict__ cw, const float* __restrict__ A,
                                const float* __restrict__ D, const float* __restrict__ bias,
                                const int* __restrict__ perm) {
    __shared__ float mre[64];
    int p = blockIdx.x;
    int t = threadIdx.x;
    if (t < 64) {
        float re = 0.f;
        for (int k = 0; k < 64; ++k) {
            int a = (k * t) & 63;
            re += D[k] * cosf((float)a * 0.0981747704246810387f);  // pi/32
        }
        mre[t] = re;
    }
    __syncthreads();
    int pp = perm[p];
    for (int k0 = t; k0 < 576; k0 += 256) {
        int sp = k0 >> 6, c = k0 & 63;
        int g = c >> 3, cil = c & 7;
        float val = 0.f;
        for (int o = 0; o < 8; ++o) {
            int oc = g * 8 + o;
            float gco = mre[(pp - oc + 64) & 63] * A[oc] * (0.125f / 64.0f);
            val += gco * cw[(oc * 8 + cil) * 9 + sp];
        }
        g_Ms[((sp * 64 + p) << 6) + (((g ^ (p & 7)) << 3) | cil)] = f2bf(val);
    }
    if (p == 0 && t < 64)
        g_b2[t] = bias[perm[t]] * 0.125f;
}

// 512 blocks x 512 thr (8 waves; (512,2) -> 1 block/CU -> 256-VGPR budget, dodging
// the 64-VGPR cap observed on ALL 1024-thr builds). Block = image x 12-row band x
// half width; 2-row steps, 4-slot circular window (LDS 124 KB). Compute: 6 waves
// (2 rows x 3 32px tiles) x mfma_f32_32x32x16 x both m-tiles (R22-verified layouts).
// Staging item map has cp in lane-low bits -> writes spread all 32 banks.
__global__ __launch_bounds__(512, 2)
void acdc_main(const float* __restrict__ x, float* __restrict__ out) {
    __shared__ __align__(16) unsigned short Mlds[9 * 64 * 64];   // 73728 B
    __shared__ __align__(16) unsigned char xsb[4 * SLOTB];       // 50176 B

    int tid = threadIdx.x;
    int lane = tid & 63, wv = tid >> 6;   // 8 waves
    // bijective XCD swizzle (512 % 8 == 0)
    int Lb = (blockIdx.x & 7) * (NBLKS / 8) + (blockIdx.x >> 3);
    int bb = Lb >> 5;                 // image
    int band = (Lb >> 1) & 15;        // 12-row band
    int half = Lb & 1;                // width half
    int h0 = band * 12;               // h0 % 4 == 0
    int cbase = half * 96;

    // ---- stage M once: 72 x 1KB chunks, 8 waves x 9 ----
    #pragma unroll
    for (int k = 0; k < 9; ++k) {
        int chunk = wv + k * 8;
        if (chunk < 72) {
            const unsigned char* src = (const unsigned char*)g_Ms + chunk * 1024 + lane * 16;
            __builtin_amdgcn_global_load_lds((as1_u32*)(const void*)src,
                (as3_u32*)(void*)((unsigned char*)Mlds + chunk * 1024), 16, 0, 0);
        }
    }

    const float* xb = x + (size_t)bb * Cn * Hn * Wn;

    // ---- prologue: rows h0-1..h0+2 -> slots 0..3 (fused load+write) ----
    // item: cp_lo = idx&3, f = (idx>>2)%26, r4 = idx/104 (rr = r4&3, cp_hi = r4>>2)
    for (int k = 0; k < 7; ++k) {
        int idx = tid + (k << 9);
        if (idx >= 3328) break;
        int cp_lo = idx & 3;
        int f = (idx >> 2) % 26;
        int r4 = idx / 104;
        int rr = r4 & 3, cp_hi = r4 >> 2;
        int cp = cp_hi * 4 + cp_lo;
        int gi = h0 - 1 + rr;
        int gc0 = cbase + 4 * f - 4;
        float av[4] = {0.f,0.f,0.f,0.f}, bv[4] = {0.f,0.f,0.f,0.f};
        bool giok = (unsigned)gi < (unsigned)Hn;
        const float* r0 = xb + ((size_t)(2 * cp) * Hn + (giok ? gi : 0)) * Wn;
        const float* r1 = r0 + Hn * Wn;
        if (giok) {
            if (gc0 >= 0 && gc0 <= Wn - 4) {
                float4 a = *(const float4*)(r0 + gc0);
                float4 b = *(const float4*)(r1 + gc0);
                av[0]=a.x; av[1]=a.y; av[2]=a.z; av[3]=a.w;
                bv[0]=b.x; bv[1]=b.y; bv[2]=b.z; bv[3]=b.w;
            } else {
                #pragma unroll
                for (int j = 0; j < 4; ++j) {
                    int gc = gc0 + j;
                    if ((unsigned)gc < (unsigned)Wn) { av[j] = r0[gc]; bv[j] = r1[gc]; }
                }
            }
        }
        int slot = rr;                       // slot(gi) = (gi+1)&3 = rr  (h0%4==0)
        int chunk = cp >> 2, sub = (cp & 3) * 4;
        #pragma unroll
        for (int j = 0; j < 4; ++j) {
            int c2 = 4 * f + j - 3;
            if ((unsigned)c2 >= (unsigned)WCOLS) continue;
            unsigned u;
            asm("v_cvt_pk_bf16_f32 %0, %1, %2" : "=v"(u) : "v"(av[j]), "v"(bv[j]));
            int key = (c2 + (c2 >> 3) + 3 * slot) & 7;
            *(unsigned*)(xsb + slot * SLOTB + c2 * 128 + ((chunk ^ key) << 4) + sub) = u;
        }
    }
    __syncthreads();   // publishes M + initial 4-row window

    int l31 = lane & 31, lh = lane >> 5;

    float4 va[4], vb[4];
    for (int t = 0; t < 6; ++t) {
        int hb = h0 + 2 * t;

        // ---- xload: rows hb+3, hb+4 to regs (retire under compute) ----
        if (t < 5) {
            #pragma unroll
            for (int k = 0; k < 4; ++k) {
                int idx = tid + (k << 9);
                va[k] = (float4){0.f,0.f,0.f,0.f};
                vb[k] = (float4){0.f,0.f,0.f,0.f};
                if (idx >= 1664) continue;
                int cp_lo = idx & 3;
                int f = (idx >> 2) % 26;
                int r2 = idx / 104;
                int rr = r2 & 1, cp_hi = r2 >> 1;
                int cp = cp_hi * 4 + cp_lo;
                int gi = hb + 3 + rr;
                int gc0 = cbase + 4 * f - 4;
                bool giok = (unsigned)gi < (unsigned)Hn;
                const float* r0 = xb + ((size_t)(2 * cp) * Hn + (giok ? gi : 0)) * Wn;
                const float* r1 = r0 + Hn * Wn;
                if (giok) {
                    if (gc0 >= 0 && gc0 <= Wn - 4) {
                        va[k] = *(const float4*)(r0 + gc0);
                        vb[k] = *(const float4*)(r1 + gc0);
                    } else {
                        float t0[4] = {0,0,0,0}, t1[4] = {0,0,0,0};
                        #pragma unroll
                        for (int j = 0; j < 4; ++j) {
                            int gc = gc0 + j;
                            if ((unsigned)gc < (unsigned)Wn) { t0[j] = r0[gc]; t1[j] = r1[gc]; }
                        }
                        va[k] = (float4){t0[0], t0[1], t0[2], t0[3]};
                        vb[k] = (float4){t1[0], t1[1], t1[2], t1[3]};
                    }
                }
            }
        }

        // ---- compute: 6 active waves; wave = (row rr, 32px tile nt); both m-tiles ----
        if (wv < 6) {
            int rr = wv & 1;
            int nt = wv >> 1;
            f32x16 acc0, acc1;
            #pragma unroll
            for (int e = 0; e < 16; ++e) { acc0[e] = 0.f; acc1[e] = 0.f; }

            #pragma unroll
            for (int sp = 0; sp < 9; ++sp) {
                const int dy = sp / 3, dx = sp % 3;
                int v = (2 * t + rr + dy) & 3;         // slot of input row hb+rr+dy-1
                int c2 = nt * 32 + l31 + dx;
                int key = (c2 + (c2 >> 3) + 3 * v) & 7;
                const unsigned char* bbase = xsb + v * SLOTB + c2 * 128;
                const unsigned char* abase = (const unsigned char*)Mlds + sp * 8192 + l31 * 128;
                #pragma unroll
                for (int ks = 0; ks < 4; ++ks) {
                    int o = 2 * ks + lh;               // k-octet (channel octet)
                    bf16x8 bfr = *(const bf16x8*)(bbase + ((o ^ key) << 4));
                    const unsigned char* ap = abase + ((o ^ (l31 & 7)) << 4);
                    bf16x8 am0 = *(const bf16x8*)ap;
                    bf16x8 am1 = *(const bf16x8*)(ap + 4096);   // p+32
                    __builtin_amdgcn_s_setprio(1);
                    acc0 = __builtin_amdgcn_mfma_f32_32x32x16_bf16(am0, bfr, acc0, 0, 0, 0);
                    acc1 = __builtin_amdgcn_mfma_f32_32x32x16_bf16(am1, bfr, acc1, 0, 0, 0);
                    __builtin_amdgcn_s_setprio(0);
                }
            }

            // ---- epilogue: +bias; C/D: ch = (r&3)+8*(r>>2)+4*lh, px = l31 (m101) ----
            int h = hb + rr;
            int pxg = cbase + nt * 32 + l31;
            #pragma unroll
            for (int r = 0; r < 16; ++r) {
                int chq = (r & 3) + 8 * (r >> 2) + 4 * lh;
                out[(((size_t)(bb * Cn + chq)) * Hn + h) * Wn + pxg]      = acc0[r] + g_b2[chq];
                out[(((size_t)(bb * Cn + 32 + chq)) * Hn + h) * Wn + pxg] = acc1[r] + g_b2[32 + chq];
            }
        }

        __syncthreads();                  // all window reads for this step done

        // ---- xwrite: rows hb+3, hb+4 into retiring slots ----
        if (t < 5) {
            #pragma unroll
            for (int k = 0; k < 4; ++k) {
                int idx = tid + (k << 9);
                if (idx >= 1664) continue;
                int cp_lo = idx & 3;
                int f = (idx >> 2) % 26;
                int r2 = idx / 104;
                int rr = r2 & 1, cp_hi = r2 >> 1;
                int cp = cp_hi * 4 + cp_lo;
                int vslot = (2 * t + rr) & 3;          // slot(hb+3+rr)
                int chunk = cp >> 2, sub = (cp & 3) * 4;
                float v0[4] = {va[k].x, va[k].y, va[k].z, va[k].w};
                float v1[4] = {vb[k].x, vb[k].y, vb[k].z, vb[k].w};
                #pragma unroll
                for (int j = 0; j < 4; ++j) {
                    int c2 = 4 * f + j - 3;
                    if ((unsigned)c2 >= (unsigned)WCOLS) continue;
                    unsigned u;
                    asm("v_cvt_pk_bf16_f32 %0, %1, %2" : "=v"(u) : "v"(v0[j]), "v"(v1[j]));
                    int key = (c2 + (c2 >> 3) + 3 * vslot) & 7;
                    *(unsigned*)(xsb + vslot * SLOTB + c2 * 128 + ((chunk ^ key) << 4) + sub) = u;
                }
            }
        }
        __syncthreads();                  // publish new rows
    }
}

extern "C" void kernel_launch(void* const* d_in, const int* in_sizes, int n_in,
                              void* d_out, int out_size, void* d_ws, size_t ws_size,
                              hipStream_t stream) {
    const float* x    = (const float*)d_in[0];
    const float* cw   = (const float*)d_in[1];
    const float* A    = (const float*)d_in[2];
    const float* D    = (const float*)d_in[3];
    const float* bias = (const float*)d_in[4];
    const int*   perm = (const int*)d_in[5];

    acdc_precompute<<<dim3(64), dim3(256), 0, stream>>>(cw, A, D, bias, perm);
    acdc_main<<<dim3(NBLKS), dim3(512), 0, stream>>>(x, (float*)d_out);
}